// Round 17
// baseline (69.967 us; speedup 1.0000x reference)
//
#include <hip/hip_runtime.h>
#include <hip/hip_bf16.h>

typedef __attribute__((ext_vector_type(8))) short bf16x8;
typedef __attribute__((ext_vector_type(4))) float f32x4;
typedef float f32x4u __attribute__((ext_vector_type(4), aligned(4))); // x rows only 4B-aligned
typedef __attribute__((ext_vector_type(4))) short short4v;
typedef unsigned short ushort_t;

#define CC 120
#define LL 469
#define HH 64

constexpr int NBATCH = 1024;
constexpr int KSTEPS = 15;

// ---- structure ----
// 512 threads = 8 waves per block; wave w owns output rows w*16 .. w*16+15.
// Halves per-wave registers (acc[12] vs acc[2][12]) -> target 4 waves/SIMD.
// phase 1: Wl[3][8192 shorts] = 49152 B triple buffer (r15/r16-proven race-free),
//          X in registers (3 named sets), depth-2, 4 VMEM/wave/region, vmcnt(4).
// phase 2: Qb @0 (16K, [128]x128B swz), Kb @16384, Vb @32768 ([64]x256B swz)
//          Pb @0 (32K) aliases Q+K after QK^T barrier; epilogue Ob f32 [120][68] @0
constexpr int WB_SHORTS   = 8192;
constexpr int SMEM_BYTES  = 49152;
constexpr int WIMG_SHORTS = KSTEPS * WB_SHORTS;    // 122880
constexpr int WIMG_BYTES  = WIMG_SHORTS * 2;       // 245760

__device__ __forceinline__ ushort_t f2bf(float f) {
  __hip_bfloat16 h = __float2bfloat16(f);
  return __builtin_bit_cast(ushort_t, h);
}

__device__ __forceinline__ void gload_lds16(const void* g, void* l) {
  __builtin_amdgcn_global_load_lds(
      (const __attribute__((address_space(1))) unsigned int*)g,
      (__attribute__((address_space(3))) unsigned int*)l, 16, 0, 0);
}

__device__ __forceinline__ char* sptr(char* base, int row, int stride, int byteoff) {
  return base + row * stride + (byteoff ^ ((row & 7) << 4));
}

// W image: per step t a 16 KB block; first 15360 B = [192 cols][40 k] bf16, rest pad.
// Step 14: shifted window k = 437+kk, kk<11 zeroed (k=437..447 covered by step 13).
__global__ void prep_w(const float* __restrict__ Wk, const float* __restrict__ Wq,
                       const float* __restrict__ Wv, ushort_t* __restrict__ wimg) {
  int idx = blockIdx.x * 256 + threadIdx.x; // 122880 exactly (480 blocks)
  int t = idx / WB_SHORTS;
  int r = idx % WB_SHORTS;
  int col = r / 40, kk = r % 40;
  float v = 0.f;
  if (r < 192 * 40 && kk < 32) {
    int kb = (t == 14) ? 437 : t * 32;
    int k = kb + kk;
    bool live = (k < LL) && (t < 14 || k >= 448);
    if (live) {
      int wsel = col >> 6, h = col & 63;
      const float* wp = (wsel == 0) ? Wk : (wsel == 1) ? Wq : Wv;
      v = wp[(size_t)k * HH + h];
    }
  }
  wimg[idx] = f2bf(v);
}

// X A-fragment: 2 vector loads into NAMED registers (one row per thread)
#define XISSUE(T, X0, X1)                                                      \
  {                                                                            \
    const int _k = (((T) == 14) ? 437 : (T) * 32) + lg * 8;                    \
    X0 = *(const f32x4u*)(xr0 + _k);                                           \
    X1 = *(const f32x4u*)(xr0 + _k + 4);                                       \
  }
// W stage into buffer (T)%3: exactly 2 gload_lds16 per thread (chunks wv*2, wv*2+1)
#define WISSUE(T)                                                              \
  {                                                                            \
    const char* _src = (const char*)(wimg + (size_t)(T) * WB_SHORTS);          \
    char* _dst = (char*)(Wl + ((T) % 3) * WB_SHORTS);                          \
    _Pragma("unroll")                                                          \
    for (int _i = 0; _i < 2; ++_i) {                                           \
      int _c = wv * 2 + _i;                                                    \
      gload_lds16(_src + _c * 1024 + lane * 16, _dst + _c * 1024);             \
    }                                                                          \
  }
#define ENDREGION(N)                                                           \
  {                                                                            \
    __builtin_amdgcn_sched_barrier(0);                                         \
    asm volatile("s_waitcnt vmcnt(" #N ")" ::: "memory");                      \
    __builtin_amdgcn_sched_barrier(0);                                         \
    __builtin_amdgcn_s_barrier();                                              \
    __builtin_amdgcn_sched_barrier(0);                                         \
  }
#define COMPUTE(T, X0, X1)                                                     \
  {                                                                            \
    const ushort_t* _wb = Wl + ((T) % 3) * WB_SHORTS;                          \
    bf16x8 _a0;                                                                \
    _Pragma("unroll")                                                          \
    for (int _j = 0; _j < 4; ++_j) {                                           \
      _a0[_j] = (short)f2bf(X0[_j]); _a0[4 + _j] = (short)f2bf(X1[_j]);        \
    }                                                                          \
    _Pragma("unroll")                                                          \
    for (int _n = 0; _n < 12; ++_n) {                                          \
      bf16x8 _b = *(const bf16x8*)(_wb + (_n * 16 + lr) * 40 + lg * 8);        \
      acc[_n] = __builtin_amdgcn_mfma_f32_16x16x32_bf16(_a0, _b, acc[_n], 0, 0, 0); \
    }                                                                          \
  }

template <bool WIMG>
__global__ __launch_bounds__(512, 4)
void fused_regional_head(const float* __restrict__ x,
                         const float* __restrict__ Wk,
                         const float* __restrict__ Wq,
                         const float* __restrict__ Wv,
                         const ushort_t* __restrict__ wimg,
                         float* __restrict__ out) {
  __shared__ char smem[SMEM_BYTES];
  const int tid = threadIdx.x;
  const int lane = tid & 63;
  const int wv = tid >> 6;   // wave 0..7, owns rows 16*wv .. 16*wv+15
  const int lr = lane & 15;
  const int lg = lane >> 4;
  const int batch = blockIdx.x;
  const size_t xbase = (size_t)batch * CC * LL;

  ushort_t* Wl = (ushort_t*)smem; // [3][8192] shorts (phase 1 only)

  const int row0 = wv * 16 + lr;                    // 0..127
  const int row0c = (row0 < CC) ? row0 : (CC - 1);  // clamp; garbage masked downstream
  const float* xr0 = x + xbase + (size_t)row0c * LL;

  // ---------------- phase 1: QKV = X @ [Wk|Wq|Wv], depth-2, 8 waves ----------------
  f32x4 acc[12];
#pragma unroll
  for (int n = 0; n < 12; ++n) acc[n] = (f32x4){0.f, 0.f, 0.f, 0.f};

  if constexpr (WIMG) {
    f32x4u xA0, xA1, xB0, xB1, xC0, xC1;
    WISSUE(0); XISSUE(0, xA0, xA1);
    WISSUE(1); XISSUE(1, xB0, xB1);
    ENDREGION(4); // drains S(0); S(1) rides through
#pragma unroll
    for (int tt = 0; tt < 4; ++tt) {
      const int t = 3 * tt;
      WISSUE(t + 2); XISSUE(t + 2, xC0, xC1);
      COMPUTE(t, xA0, xA1);
      ENDREGION(4);
      WISSUE(t + 3); XISSUE(t + 3, xA0, xA1);
      COMPUTE(t + 1, xB0, xB1);
      ENDREGION(4);
      WISSUE(t + 4); XISSUE(t + 4, xB0, xB1);
      COMPUTE(t + 2, xC0, xC1);
      ENDREGION(4);
    }
    WISSUE(14); XISSUE(14, xC0, xC1);
    COMPUTE(12, xA0, xA1);
    ENDREGION(4);
    COMPUTE(13, xB0, xB1);
    ENDREGION(0);
    COMPUTE(14, xC0, xC1);
  } else {
    // slow fallback (unused when ws present)
    for (int t = 0; t < KSTEPS; ++t) {
      const int kb = (t == 14) ? 437 : t * 32;
      f32x4u x0 = *(const f32x4u*)(xr0 + kb + lg * 8);
      f32x4u x1 = *(const f32x4u*)(xr0 + kb + lg * 8 + 4);
      bf16x8 a0;
#pragma unroll
      for (int j = 0; j < 4; ++j) {
        a0[j] = (short)f2bf(x0[j]); a0[4 + j] = (short)f2bf(x1[j]);
      }
#pragma unroll
      for (int n = 0; n < 12; ++n) {
        int col = n * 16 + lr;
        int wsel = col >> 6, h = col & 63;
        const float* wp = (wsel == 0) ? Wk : (wsel == 1) ? Wq : Wv;
        bf16x8 b;
#pragma unroll
        for (int j = 0; j < 8; ++j) {
          int k = kb + lg * 8 + j;
          bool live = (k < LL) && (t < 14 || k >= 448);
          b[j] = (short)f2bf(live ? wp[(size_t)k * HH + h] : 0.f);
        }
        acc[n] = __builtin_amdgcn_mfma_f32_16x16x32_bf16(a0, b, acc[n], 0, 0, 0);
      }
    }
  }
  __syncthreads(); // W region dead; phase-2 tiles take over

  // ---------------- write Q,K,V (bf16, swizzled) ----------------
  char* Qb = smem;
  char* Kb = smem + 16384;
  char* Vb = smem + 32768;
  char* Pb = smem;
#pragma unroll
  for (int r = 0; r < 4; ++r) {
    int row = wv * 16 + lg * 4 + r; // acc D-layout: M-index lg*4+r of this wave's 16-row band
#pragma unroll
    for (int n = 0; n < 4; ++n) {
      *(ushort_t*)sptr(Kb, row, 128, (n * 16 + lr) * 2) = f2bf(acc[n][r]);
      *(ushort_t*)sptr(Qb, row, 128, (n * 16 + lr) * 2) = f2bf(acc[4 + n][r]);
    }
  }
  // V^T packed: 4 consecutive c-rows -> ds_write_b64
#pragma unroll
  for (int n = 0; n < 4; ++n) {
    short4v pk;
#pragma unroll
    for (int r = 0; r < 4; ++r) pk[r] = (short)f2bf(acc[8 + n][r]);
    *(short4v*)sptr(Vb, n * 16 + lr, 256, (wv * 16 + lg * 4) * 2) = pk;
  }
  __syncthreads();

  // ---------------- QK^T ----------------
  f32x4 accw[8];
#pragma unroll
  for (int n = 0; n < 8; ++n) accw[n] = (f32x4){0.f, 0.f, 0.f, 0.f};
#pragma unroll
  for (int ks = 0; ks < 2; ++ks) {
    bf16x8 a0 = *(const bf16x8*)sptr(Qb, wv * 16 + lr, 128, ks * 64 + lg * 16);
#pragma unroll
    for (int n = 0; n < 8; ++n) {
      bf16x8 b = *(const bf16x8*)sptr(Kb, n * 16 + lr, 128, ks * 64 + lg * 16);
      accw[n] = __builtin_amdgcn_mfma_f32_16x16x32_bf16(a0, b, accw[n], 0, 0, 0);
    }
  }
  __syncthreads(); // all done reading Q/K before P overwrites

  // ---------------- softmax (wave-parallel over 16-lane col groups) ----------------
#pragma unroll
  for (int r = 0; r < 4; ++r) {
    float l[8];
    float m = -1e30f;
#pragma unroll
    for (int n = 0; n < 8; ++n) {
      float v = accw[n][r] * 0.125f;
      if (n == 7 && lr >= 8) v = -1e30f; // col = 112+lr >= 120 masked
      l[n] = v;
      m = fmaxf(m, v);
    }
#pragma unroll
    for (int off = 1; off < 16; off <<= 1) m = fmaxf(m, __shfl_xor(m, off));
    float s = 0.f;
#pragma unroll
    for (int n = 0; n < 8; ++n) {
      float p = __expf(l[n] - m);
      l[n] = p;
      s += p;
    }
#pragma unroll
    for (int off = 1; off < 16; off <<= 1) s += __shfl_xor(s, off);
    float inv = 1.f / s;
    int row = wv * 16 + lg * 4 + r;
#pragma unroll
    for (int n = 0; n < 8; ++n)
      *(ushort_t*)sptr(Pb, row, 256, (n * 16 + lr) * 2) = f2bf(l[n] * inv);
  }
  // no barrier: each wave reads only its own P rows; V covered by barrier above

  // ---------------- out = P @ V ----------------
  f32x4 acco[4];
#pragma unroll
  for (int n = 0; n < 4; ++n) acco[n] = (f32x4){0.f, 0.f, 0.f, 0.f};
#pragma unroll
  for (int ks = 0; ks < 4; ++ks) {
    bf16x8 a0 = *(const bf16x8*)sptr(Pb, wv * 16 + lr, 256, ks * 64 + lg * 16);
#pragma unroll
    for (int n = 0; n < 4; ++n) {
      bf16x8 b = *(const bf16x8*)sptr(Vb, n * 16 + lr, 256, ks * 64 + lg * 16);
      acco[n] = __builtin_amdgcn_mfma_f32_16x16x32_bf16(a0, b, acco[n], 0, 0, 0);
    }
  }

  // ---------------- epilogue: LDS transpose -> float4 coalesced stores ----------------
  __syncthreads(); // P/V dead
  float* Ob = (float*)smem; // [120][68] f32
#pragma unroll
  for (int r = 0; r < 4; ++r) {
    int row = wv * 16 + lg * 4 + r;
    if (row < CC) {
#pragma unroll
      for (int n = 0; n < 4; ++n)
        Ob[row * 68 + n * 16 + lr] = acco[n][r];
    }
  }
  __syncthreads();
  const size_t obase = (size_t)batch * CC * HH;
#pragma unroll
  for (int i = 0; i < 4; ++i) {
    int idx = i * 512 + tid; // float4 index, 1920 total
    if (idx < 1920) {
      int row = idx >> 4;
      int c4 = (idx & 15) * 4;
      f32x4 v = *(const f32x4*)(Ob + row * 68 + c4);
      *(f32x4*)(out + obase + (size_t)idx * 4) = v;
    }
  }
}

extern "C" void kernel_launch(void* const* d_in, const int* in_sizes, int n_in,
                              void* d_out, int out_size, void* d_ws, size_t ws_size,
                              hipStream_t stream) {
  (void)in_sizes; (void)n_in; (void)out_size;
  const float* x  = (const float*)d_in[0];
  const float* Wk = (const float*)d_in[1];
  const float* Wq = (const float*)d_in[2];
  const float* Wv = (const float*)d_in[3];
  float* out = (float*)d_out;
  if (ws_size >= (size_t)WIMG_BYTES && d_ws != nullptr) {
    ushort_t* wimg = (ushort_t*)d_ws;
    prep_w<<<480, 256, 0, stream>>>(Wk, Wq, Wv, wimg);
    fused_regional_head<true><<<NBATCH, 512, 0, stream>>>(x, Wk, Wq, Wv, wimg, out);
  } else {
    fused_regional_head<false><<<NBATCH, 512, 0, stream>>>(x, Wk, Wq, Wv, nullptr, out);
  }
}